// Round 8
// baseline (665.611 us; speedup 1.0000x reference)
//
#include <hip/hip_runtime.h>
#include <math.h>

#define THETA 0.6f
typedef unsigned short u16;
typedef unsigned int u32;
typedef __attribute__((ext_vector_type(8))) short bf16x8;
typedef __attribute__((ext_vector_type(4))) float f32x4;

__device__ __forceinline__ float sigm(float x){ return 1.0f/(1.0f+__expf(-x)); }
__device__ __forceinline__ float siluf(float x){ return x*sigm(x); }
__device__ __forceinline__ float softplusf(float x){ return x>20.0f ? x : log1pf(__expf(x)); }
__device__ __forceinline__ u16 f2b(float x){
  u32 u = __float_as_uint(x);
  u32 r = (u + 0x7FFFu + ((u>>16)&1u)) >> 16;
  return (u16)r;
}
#define LOG2E 1.44269504f

// ---------------- K1: dual layernorm (rows of 96), one wave per row ----------------
__global__ __launch_bounds__(256) void k_ln(const float* __restrict__ in0, const float* __restrict__ in1,
     const float* __restrict__ g, const float* __restrict__ bb,
     float* __restrict__ xc, float* __restrict__ xt, float* __restrict__ out1){
  int wave = threadIdx.x>>6, lane = threadIdx.x&63;
  int row = blockIdx.x*4 + wave;           // 0..16383
  int which = row >= 8192;
  int r = which ? row - 8192 : row;
  const float* src = which ? in1 : in0;
  float v0 = src[(long)r*96 + lane];
  float v1 = (lane<32) ? src[(long)r*96 + 64 + lane] : 0.0f;
  float s = v0+v1, s2 = v0*v0+v1*v1;
  for (int m=1; m<64; m<<=1){ s += __shfl_xor(s, m); s2 += __shfl_xor(s2, m); }
  float mean = s*(1.0f/96.0f);
  float var = fmaxf(s2*(1.0f/96.0f) - mean*mean, 0.0f);
  float rstd = rsqrtf(var + 1e-6f);
  float y0 = (v0-mean)*rstd*g[lane] + bb[lane];
  float y1 = 0.f;
  if (lane<32) y1 = (v1-mean)*rstd*g[64+lane] + bb[64+lane];
  if (!which){
    xc[(long)r*96+lane] = y0;
    if (lane<32) xc[(long)r*96+64+lane] = y1;
  } else {
    xt[(long)r*96+lane] = y0; out1[(long)r*96+lane] = y0;
    if (lane<32){ xt[(long)r*96+64+lane] = y1; out1[(long)r*96+64+lane] = y1; }
  }
}

// ---------------- K2: xz = xc @ in_proj_w (8192x96 @ 96x384), 32-row tiles ----------------
__global__ __launch_bounds__(256) void k_inproj(const float* __restrict__ xc, const float* __restrict__ w,
     float* __restrict__ xpre, float* __restrict__ z){
  __shared__ __align__(16) float At[32*97];
  __shared__ __align__(16) float Bt[96*64];
  int tid = threadIdx.x; int tx = tid&15, ty = tid>>4;
  long rowbase = (long)blockIdx.x*32;
  for (int idx=tid; idx<32*96; idx+=256){ int r=idx/96, c=idx-r*96; At[r*97+c] = xc[(rowbase+r)*96+c]; }
  for (int nc=0; nc<6; ++nc){
    __syncthreads();
    for (int idx=tid; idx<96*64; idx+=256){ int kk=idx>>6, cc=idx&63; Bt[idx] = w[kk*384 + nc*64 + cc]; }
    __syncthreads();
    float acc[2][4] = {};
    for (int kk=0; kk<96; ++kk){
      float a0=At[(ty*2+0)*97+kk], a1=At[(ty*2+1)*97+kk];
      const float4 bv = *(const float4*)&Bt[kk*64 + tx*4];
      acc[0][0]+=a0*bv.x; acc[0][1]+=a0*bv.y; acc[0][2]+=a0*bv.z; acc[0][3]+=a0*bv.w;
      acc[1][0]+=a1*bv.x; acc[1][1]+=a1*bv.y; acc[1][2]+=a1*bv.z; acc[1][3]+=a1*bv.w;
    }
    for (int i=0;i<2;++i){
      long row = rowbase + ty*2 + i; int b = (int)(row>>12); int hw = (int)(row&4095);
      for (int j=0;j<4;++j){
        int n = nc*64 + tx*4 + j; float v = acc[i][j];
        if (n<192) xpre[((long)(b*192+n)<<12) + hw] = v;
        else z[row*192 + (n-192)] = v;
      }
    }
  }
}

// ---------------- K3a: depthwise 3x3 conv on x (NCHW) + silu -> x_t[:, :, 0, :] ----------------
__global__ __launch_bounds__(256) void k_convx(const float* __restrict__ xpre, const float* __restrict__ wc,
     const float* __restrict__ bc, float* __restrict__ xtt){
  int idx = blockIdx.x*256 + threadIdx.x;  // < 2*192*4096
  int hw = idx & 4095; int d = (idx>>12)%192; int b = idx/(4096*192);
  int h = hw>>6, w = hw&63;
  float acc = bc[d];
  const float* src = xpre + ((long)(b*192+d)<<12);
  for (int dh=0; dh<3; ++dh){ int hh=h+dh-1; if (hh<0||hh>63) continue;
    for (int dw=0; dw<3; ++dw){ int ww=w+dw-1; if (ww<0||ww>63) continue;
      acc += wc[d*9+dh*3+dw]*src[hh*64+ww]; } }
  xtt[((long)(b*192+d)<<13) + hw] = siluf(acc);
}

// ---------------- K3b: grouped 3x3 conv on xt (NHWC input, groups=96, 2 out/ch) + silu ----------------
__global__ __launch_bounds__(256) void k_convxt(const float* __restrict__ xtn, const float* __restrict__ wc,
     const float* __restrict__ bc, float* __restrict__ xtt){
  int idx = blockIdx.x*256 + threadIdx.x;
  int hw = idx & 4095; int o = (idx>>12)%192; int b = idx/(4096*192);
  int h = hw>>6, w = hw&63; int ci = o>>1;
  float acc = bc[o];
  for (int dh=0; dh<3; ++dh){ int hh=h+dh-1; if (hh<0||hh>63) continue;
    for (int dw=0; dw<3; ++dw){ int ww=w+dw-1; if (ww<0||ww>63) continue;
      acc += wc[o*9+dh*3+dw]*xtn[((long)((b*64+hh)*64+ww))*96 + ci]; } }
  xtt[((long)(b*192+o)<<13) + 4096 + hw] = siluf(acc);
}

// ---------------- K4a: kd_t[i*152+m] ----------------
__global__ __launch_bounds__(256) void k_kd(const float* __restrict__ w, float* __restrict__ kdt){
  int idx = blockIdx.x*256 + threadIdx.x;
  if (idx >= 152*192) return;
  const float* p = w + (long)idx*18;
  float s = 0.f;
  #pragma unroll
  for (int j=0;j<18;++j) s += p[j];
  int m = idx/192, i = idx - m*192;
  kdt[i*152 + m] = s;
}

// ---------------- generic zero ----------------
__global__ __launch_bounds__(256) void k_zero(float4* __restrict__ p, int n4){
  int i = blockIdx.x*256 + threadIdx.x;
  if (i<n4) p[i] = make_float4(0.f,0.f,0.f,0.f);
}

// ---------------- K4x: xtt -> padded NHWC bf16 XTNP[b][t][cc][4356 rows][40ch] ----------------
__global__ __launch_bounds__(256) void k_xtn(const float* __restrict__ xtt, u16* __restrict__ xtnp){
  __shared__ float tl[64][33];
  int tid = threadIdx.x;
  int h = blockIdx.x;        // 0..63
  int cc = blockIdx.y;       // 0..5
  int b = blockIdx.z>>1, t = blockIdx.z&1;
  for (int i=tid; i<2048; i+=256){ int ch=i>>6, w=i&63;
    tl[w][ch] = xtt[((long)(b*192 + cc*32+ch)<<13) + t*4096 + h*64 + w]; }
  __syncthreads();
  long plane = (long)((b*2+t)*6+cc)*174240;
  uint4* dst = (uint4*)(xtnp + plane);
  for (int i=tid; i<320; i+=256){
    int w = i/5, chunk = i - (i/5)*5;
    uint4 v = {0u,0u,0u,0u};
    if (chunk<4){
      int c0 = chunk*8;
      v.x = (u32)f2b(tl[w][c0+0]) | ((u32)f2b(tl[w][c0+1])<<16);
      v.y = (u32)f2b(tl[w][c0+2]) | ((u32)f2b(tl[w][c0+3])<<16);
      v.z = (u32)f2b(tl[w][c0+4]) | ((u32)f2b(tl[w][c0+5])<<16);
      v.w = (u32)f2b(tl[w][c0+6]) | ((u32)f2b(tl[w][c0+7])<<16);
    }
    dst[((h+1)*66 + (w+1))*5 + chunk] = v;
  }
}

// ---------------- K4w: weights -> bf16 WB[kg][t][cc][tap10][48m][40ch]; tap9 = kd ----------------
__global__ __launch_bounds__(256) void k_wb(const float* __restrict__ xpw, const float* __restrict__ kdt,
     u16* __restrict__ wb){
  int idx = blockIdx.x*256 + threadIdx.x;
  if (idx >= 921600) return;
  int sl = idx%40; int rest = idx/40;
  int mm = rest%48; rest /= 48;
  int tap = rest%10; rest /= 10;
  int cc = rest%6; rest /= 6;
  int t = rest%2; int kg = rest/2;
  u16 v = 0;
  if (sl<32 && mm<38){
    int ch = cc*32+sl; int m = kg*38+mm;
    float f = (tap<9) ? xpw[(long)m*3456 + ch*18 + t*9 + tap] : kdt[ch*152 + m];
    v = f2b(f);
  }
  wb[idx] = v;
}

// ---------------- K4b: x_dbl += out_n - theta*out_d via bf16 MFMA ----------------
__global__ __launch_bounds__(256) void k_outn(const u16* __restrict__ xtnp, const u16* __restrict__ wb,
     float* __restrict__ xdbl){
  __shared__ __align__(16) u16 Bl[264*40];     // 21120 B
  __shared__ __align__(16) u16 Al[10*48*40];   // 38400 B
  int tid = threadIdx.x, wv = tid>>6, lane = tid&63;
  int n = lane&15, kq = lane>>4;
  int hp = blockIdx.x, b = blockIdx.y;
  int kg = blockIdx.z>>1, t = blockIdx.z&1;
  f32x4 accN[2][3], accD[2][3];
  #pragma unroll
  for (int q=0;q<2;++q)
    #pragma unroll
    for (int mt=0;mt<3;++mt){ accN[q][mt] = (f32x4){0.f,0.f,0.f,0.f}; accD[q][mt] = (f32x4){0.f,0.f,0.f,0.f}; }

  for (int cc=0; cc<6; ++cc){
    const float4* srcB = (const float4*)(xtnp + (long)((b*2+t)*6+cc)*174240 + (long)hp*132*40);
    const float4* srcA = (const float4*)(wb + (long)((kg*2+t)*6+cc)*19200);
    float4 tb[6]; float4 ta[10];
    #pragma unroll
    for (int q=0;q<6;++q){ int ix = tid + q*256; if (ix<1320) tb[q] = srcB[ix]; }
    #pragma unroll
    for (int q=0;q<10;++q){ int ix = tid + q*256; if (ix<2400) ta[q] = srcA[ix]; }
    __syncthreads();
    #pragma unroll
    for (int q=0;q<6;++q){ int ix = tid + q*256; if (ix<1320) ((float4*)Bl)[ix] = tb[q]; }
    #pragma unroll
    for (int q=0;q<10;++q){ int ix = tid + q*256; if (ix<2400) ((float4*)Al)[ix] = ta[q]; }
    __syncthreads();
    #pragma unroll
    for (int tap=0; tap<10; ++tap){
      int dh = (tap<9) ? tap/3 : 1;
      int dw = (tap<9) ? (tap - (tap/3)*3) : 1;
      bf16x8 a0 = *(const bf16x8*)&Al[(tap*48 +  0 + n)*40 + kq*8];
      bf16x8 a1 = *(const bf16x8*)&Al[(tap*48 + 16 + n)*40 + kq*8];
      bf16x8 a2 = *(const bf16x8*)&Al[(tap*48 + 32 + n)*40 + kq*8];
      bf16x8 b0 = *(const bf16x8*)&Bl[((0+dh)*66 + wv*16 + dw + n)*40 + kq*8];
      bf16x8 b1 = *(const bf16x8*)&Bl[((1+dh)*66 + wv*16 + dw + n)*40 + kq*8];
      if (tap<9){
        accN[0][0] = __builtin_amdgcn_mfma_f32_16x16x32_bf16(a0, b0, accN[0][0], 0,0,0);
        accN[0][1] = __builtin_amdgcn_mfma_f32_16x16x32_bf16(a1, b0, accN[0][1], 0,0,0);
        accN[0][2] = __builtin_amdgcn_mfma_f32_16x16x32_bf16(a2, b0, accN[0][2], 0,0,0);
        accN[1][0] = __builtin_amdgcn_mfma_f32_16x16x32_bf16(a0, b1, accN[1][0], 0,0,0);
        accN[1][1] = __builtin_amdgcn_mfma_f32_16x16x32_bf16(a1, b1, accN[1][1], 0,0,0);
        accN[1][2] = __builtin_amdgcn_mfma_f32_16x16x32_bf16(a2, b1, accN[1][2], 0,0,0);
      } else {
        accD[0][0] = __builtin_amdgcn_mfma_f32_16x16x32_bf16(a0, b0, accD[0][0], 0,0,0);
        accD[0][1] = __builtin_amdgcn_mfma_f32_16x16x32_bf16(a1, b0, accD[0][1], 0,0,0);
        accD[0][2] = __builtin_amdgcn_mfma_f32_16x16x32_bf16(a2, b0, accD[0][2], 0,0,0);
        accD[1][0] = __builtin_amdgcn_mfma_f32_16x16x32_bf16(a0, b1, accD[1][0], 0,0,0);
        accD[1][1] = __builtin_amdgcn_mfma_f32_16x16x32_bf16(a1, b1, accD[1][1], 0,0,0);
        accD[1][2] = __builtin_amdgcn_mfma_f32_16x16x32_bf16(a2, b1, accD[1][2], 0,0,0);
      }
    }
    __syncthreads();
  }
  #pragma unroll
  for (int q=0;q<2;++q){
    int hw = (hp*2+q)*64 + wv*16 + n;
    #pragma unroll
    for (int mt=0; mt<3; ++mt){
      #pragma unroll
      for (int r=0;r<4;++r){
        int m = mt*16 + kq*4 + r;
        if (m<38){
          long base = ((long)((b*4+kg)*38+m)<<13) + hw;
          float vN = accN[q][mt][r];
          float vD = accD[q][mt][r];
          unsafeAtomicAdd(&xdbl[base + t*4096], vN - THETA*vD);
          unsafeAtomicAdd(&xdbl[base + (1-t)*4096], vN);
        }
      }
    }
  }
}

// ---------------- K6a: chunked scan pass A. C=8 chunks of 1024, LDS diet: reg-staged B/C ----------------
__global__ __launch_bounds__(64) void k_scan_a(const float* __restrict__ xdbl, const float* __restrict__ xtt,
    const float* __restrict__ dt_w, const float* __restrict__ dt_b, const float* __restrict__ A_logs,
    const float* __restrict__ Ds, float* __restrict__ outy, float* __restrict__ Sg,
    float* __restrict__ hend, float* __restrict__ send){
  __shared__ __align__(16) float2 ddu[4][36];   // {delta, delta*u}; row 288B
  __shared__ __align__(16) float P[4][328];     // row stride 328 -> n+8dl banks (<=2-way)
  __shared__ float dtsl[6][33];
  __shared__ float uls[4][33];
  __shared__ float dtwl[4][6]; __shared__ float dtbl[4]; __shared__ float Dl[4];
  int tid = threadIdx.x; int n = tid&15; int dl = tid>>4;
  int th = tid&31, hf = tid>>5;
  int dg = blockIdx.x; int k = blockIdx.y; int zz = blockIdx.z;
  int b = zz>>3; int c = zz&7;
  int dbase = dg*4; bool rev = (k&1);
  if (tid<24) dtwl[tid/6][tid%6] = dt_w[(k*192 + dbase + tid/6)*6 + tid%6];
  else if (tid<28) dtbl[tid-24] = dt_b[k*192 + dbase + tid-24];
  else if (tid<32) Dl[tid-28] = Ds[k*192 + dbase + tid-28];
  float Aval2 = -__expf(A_logs[(k*192 + dbase + dl)*16 + n]) * LOG2E;
  const float* xrow = xdbl + ((long)((b*4+k)*38)<<13);
  const float* Brow = xrow + ((long)(6+n)<<13);
  const float* Crow = xrow + ((long)(22+n)<<13);
  float h = 0.f;
  float Scar0 = 0.f, Scar1 = 0.f;
  float* Prow = &P[dl][n];
  __syncthreads();
  for (int ph=0; ph<32; ++ph){
    int l0 = c*1024 + ph*32;
    // ---- register-stage B/C for the whole 32-step phase (per-lane rows) ----
    float Brf[32], Crf[32];
    #pragma unroll
    for (int q=0;q<8;++q) *(float4*)&Brf[q*4] = *(const float4*)&Brow[l0 + q*4];
    #pragma unroll
    for (int q=0;q<8;++q) *(float4*)&Crf[q*4] = *(const float4*)&Crow[l0 + q*4];
    // ---- stage dts (6x32), u (4x32) ----
    #pragma unroll
    for (int q=0;q<3;++q){ int r = q*2+hf; dtsl[r][th] = xrow[((long)r<<13) + l0 + th]; }
    #pragma unroll
    for (int q=0;q<2;++q){ int j = q*2+hf;
      long li = rev ? (long)(8191-(l0+th)) : (long)(l0+th);
      uls[j][th] = xtt[((long)(b*192 + dbase + j)<<13) + li];
    }
    __syncthreads();
    // ---- delta, du, prefix-sum S ----
    {
      float s0 = dtbl[hf], s1 = dtbl[hf+2];
      #pragma unroll
      for (int r=0;r<6;++r){ float dv = dtsl[r][th]; s0 += dv*dtwl[hf][r]; s1 += dv*dtwl[hf+2][r]; }
      float d0 = softplusf(s0), d1 = softplusf(s1);
      ddu[hf][th]   = make_float2(d0, d0*uls[hf][th]);
      ddu[hf+2][th] = make_float2(d1, d1*uls[hf+2][th]);
      float p0 = d0, p1 = d1;
      #pragma unroll
      for (int d=1; d<32; d<<=1){
        float t0 = __shfl_up(p0, d, 32), t1 = __shfl_up(p1, d, 32);
        if (th>=d){ p0 += t0; p1 += t1; }
      }
      if (c > 0){
        long ch0 = (long)((b*4+k)*192 + dbase + hf);
        long off = (long)(c-1)*1024 + ph*32 + th;
        Sg[ch0*7168 + off] = Scar0 + p0;
        Sg[(ch0+2)*7168 + off] = Scar1 + p1;
      }
      Scar0 += __shfl(p0, 31, 32); Scar1 += __shfl(p1, 31, 32);
    }
    __syncthreads();
    // ---- 2 half-phases of 16 steps ----
    #pragma unroll
    for (int h2=0; h2<2; ++h2){
      int base = h2*16;
      #pragma unroll
      for (int u2=0; u2<16; u2+=2){
        int s = base + u2;
        float4 dd = *(const float4*)&ddu[dl][s];   // {delta_s, du_s, delta_s1, du_s1}
        float a0 = exp2f(dd.x * Aval2);
        h = fmaf(a0, h, dd.y * Brf[s]);
        Prow[u2*20] = h * Crf[s];
        float a1 = exp2f(dd.z * Aval2);
        h = fmaf(a1, h, dd.w * Brf[s+1]);
        Prow[(u2+1)*20] = h * Crf[s+1];
      }
      __syncthreads();
      {
        int j = tid>>4, tq = tid&15;
        const float4* pr = (const float4*)&P[j][tq*20];
        float4 q0=pr[0], q1=pr[1], q2=pr[2], q3=pr[3];
        float y = ((q0.x+q0.y)+(q0.z+q0.w)) + ((q1.x+q1.y)+(q1.z+q1.w))
                + ((q2.x+q2.y)+(q2.z+q2.w)) + ((q3.x+q3.y)+(q3.z+q3.w));
        int tt = base + tq;
        outy[((long)((b*4+k)*192 + dbase + j)<<13) + l0 + tt] = y + Dl[j]*uls[j][tt];
      }
      __syncthreads();
    }
  }
  int chain = (b*4+k)*192 + dbase + dl;
  hend[c*24576 + chain*16 + n] = h;
  if (th==0){
    int chb = (b*4+k)*192 + dbase;
    send[c*1536 + chb + hf] = Scar0;
    send[c*1536 + chb + hf + 2] = Scar1;
  }
}

// ---------------- K6b: carry propagation across the 8 chunks ----------------
__global__ __launch_bounds__(256) void k_scan_b(const float* __restrict__ A_logs,
    const float* __restrict__ hend, const float* __restrict__ send, float* __restrict__ h0g){
  int idx = blockIdx.x*256 + threadIdx.x;   // < 24576
  int chain = idx>>4, n = idx&15;
  int d = chain%192; int kk = (chain/192)&3;
  float A2 = -__expf(A_logs[(kk*192+d)*16+n]) * LOG2E;
  float h0 = 0.f;
  #pragma unroll
  for (int c=0;c<7;++c){
    h0 = exp2f(A2*send[c*1536+chain])*h0 + hend[c*24576+idx];
    h0g[(c+1)*24576 + idx] = h0;
  }
}

// ---------------- K6c: fix-up y[t] += sum_n C[t,n]*exp(A_n*S[t])*h0[n] for chunks 1..7 ----------------
__global__ __launch_bounds__(128) void k_scan_c(const float* __restrict__ xdbl,
    const float* __restrict__ A_logs, const float* __restrict__ Sg, const float* __restrict__ h0g,
    float* __restrict__ outy){
  __shared__ float Cl[16][128];
  __shared__ float h0l[192][16];
  __shared__ float Al[192][16];
  int tid = threadIdx.x;
  int tt0 = blockIdx.x*128; int c = blockIdx.y+1; int z = blockIdx.z;
  int b = z>>2, k = z&3;
  const float* xrow = xdbl + ((long)((b*4+k)*38)<<13);
  for (int idx=tid; idx<2048; idx+=128){
    int nn = idx>>7, t = idx&127;
    Cl[nn][t] = xrow[((long)(22+nn)<<13) + c*1024 + tt0 + t];
  }
  for (int idx=tid; idx<3072; idx+=128){
    int d = idx>>4, nn = idx&15;
    h0l[d][nn] = h0g[c*24576 + ((b*4+k)*192+d)*16 + nn];
    Al[d][nn]  = -__expf(A_logs[(k*192+d)*16+nn]) * LOG2E;
  }
  __syncthreads();
  int t = tid;
  for (int d=0; d<192; ++d){
    long chain = (long)((b*4+k)*192 + d);
    float S = Sg[chain*7168 + (long)(c-1)*1024 + tt0 + t];
    float acc = 0.f;
    #pragma unroll
    for (int nn=0; nn<16; ++nn) acc += Cl[nn][t]*exp2f(Al[d][nn]*S)*h0l[d][nn];
    long yi = (chain<<13) + c*1024 + tt0 + t;
    outy[yi] += acc;
  }
}

// ---------------- K7a: per-frame 64x64 spatial transpose of out_y[k=1] and out_y[k=3] ----------------
__global__ __launch_bounds__(256) void k_transp(const float* __restrict__ outy, float* __restrict__ T1,
     float* __restrict__ T3){
  __shared__ float tl[64*65];
  int idx = blockIdx.x;         // < 1536
  int t = idx&1; int q = idx>>1; int d = q%192; int r2 = q/192; int ksel = r2&1; int b = r2>>1;
  int k = ksel ? 3 : 1;
  const float* src = outy + ((long)((b*4+k)*192 + d)<<13) + t*4096;
  float* dst = (ksel ? T3 : T1) + ((long)(b*192 + d)<<13) + t*4096;
  int tid = threadIdx.x;
  for (int i=tid; i<4096; i+=256){ int r=i>>6, c=i&63; tl[c*65+r] = src[i]; }
  __syncthreads();
  for (int i=tid; i<4096; i+=256){ int r=i>>6, c=i&63; dst[i] = tl[r*65+c]; }
}

// ---------------- K7b: 8-term combine + out-LN + silu(z) gate -> Y (B,HW,192) ----------------
__global__ __launch_bounds__(256) void k_combine(const float* __restrict__ outy,
    const float* __restrict__ T1, const float* __restrict__ T3,
    const float* __restrict__ z, const float* __restrict__ ong, const float* __restrict__ onb,
    float* __restrict__ Y){
  __shared__ float yt[32][193];
  __shared__ float redl[32][8][2];
  __shared__ float stats[32][2];
  int tid = threadIdx.x;
  int tx = tid&31, ty = tid>>5;
  int b = blockIdx.y;
  long pg = (long)(blockIdx.x&127)*32 + tx;
  float s = 0.f, s2 = 0.f;
  #pragma unroll 4
  for (int dc=0; dc<24; ++dc){
    int d = dc*8 + ty;
    const float* r0 = outy + ((long)(b*768 + d)<<13);
    const float* r2 = outy + ((long)(b*768 + 384 + d)<<13);
    const float* t1 = T1 + ((long)(b*192 + d)<<13);
    const float* t3 = T3 + ((long)(b*192 + d)<<13);
    float v = r0[pg] + r0[4096+pg] + r2[8191-pg] + r2[4095-pg]
            + t1[pg] + t1[4096+pg] + t3[8191-pg] + t3[4095-pg];
    yt[tx][d] = v; s += v; s2 += v*v;
  }
  redl[tx][ty][0] = s; redl[tx][ty][1] = s2;
  __syncthreads();
  if (tid<32){
    float S=0.f, S2=0.f;
    #pragma unroll
    for (int g=0; g<8; ++g){ S += redl[tid][g][0]; S2 += redl[tid][g][1]; }
    float m = S*(1.f/192.f);
    float var = fmaxf(S2*(1.f/192.f) - m*m, 0.f);
    stats[tid][0] = m; stats[tid][1] = rsqrtf(var + 1e-5f);
  }
  __syncthreads();
  long rowbase = (long)b*4096 + (blockIdx.x&127)*32;
  #pragma unroll 4
  for (int idx=tid; idx<32*192; idx+=256){
    int r = idx/192, d = idx - r*192;
    float v = (yt[r][d] - stats[r][0])*stats[r][1]*ong[d] + onb[d];
    float zv = z[(rowbase+r)*192 + d];
    Y[(rowbase+r)*192 + d] = v*(zv*sigm(zv));
  }
}

// ---------------- K7c: out0 = xc + Y @ wout (8192x192 @ 192x96) ----------------
__global__ __launch_bounds__(256) void k_outproj(const float* __restrict__ Y,
    const float* __restrict__ xc, const float* __restrict__ wout, float* __restrict__ out0){
  __shared__ float Yl[32][193];
  __shared__ __align__(16) float Wl[48*96];
  int tid = threadIdx.x;
  int r = tid>>3, cq = tid&7;
  long rowbase = (long)blockIdx.x*32;
  for (int idx=tid; idx<32*192; idx+=256){
    int rr = idx/192, d = idx - rr*192;
    Yl[rr][d] = Y[(rowbase+rr)*192 + d];
  }
  float acc[12] = {};
  for (int db=0; db<192; db+=48){
    __syncthreads();
    for (int idx=tid; idx<48*96; idx+=256) Wl[idx] = wout[db*96 + idx];
    __syncthreads();
    #pragma unroll 4
    for (int dd=0; dd<48; ++dd){
      float yv = Yl[r][db+dd];
      const float4* wr = (const float4*)&Wl[dd*96 + cq*12];
      float4 w0=wr[0], w1=wr[1], w2=wr[2];
      acc[0]+=yv*w0.x; acc[1]+=yv*w0.y; acc[2]+=yv*w0.z;  acc[3]+=yv*w0.w;
      acc[4]+=yv*w1.x; acc[5]+=yv*w1.y; acc[6]+=yv*w1.z;  acc[7]+=yv*w1.w;
      acc[8]+=yv*w2.x; acc[9]+=yv*w2.y; acc[10]+=yv*w2.z; acc[11]+=yv*w2.w;
    }
  }
  long ob = (rowbase + r)*96 + cq*12;
  #pragma unroll
  for (int j=0;j<12;++j) out0[ob+j] = xc[ob+j] + acc[j];
}

extern "C" void kernel_launch(void* const* d_in, const int* in_sizes, int n_in,
                              void* d_out, int out_size, void* d_ws, size_t ws_size,
                              hipStream_t stream) {
  const float* input0    = (const float*)d_in[0];
  const float* input1    = (const float*)d_in[1];
  const float* ln1_g     = (const float*)d_in[2];
  const float* ln1_b     = (const float*)d_in[3];
  const float* in_proj_w = (const float*)d_in[4];
  const float* conv2d_w  = (const float*)d_in[5];
  const float* conv2d_b  = (const float*)d_in[6];
  const float* conv2dxt_w= (const float*)d_in[7];
  const float* conv2dxt_b= (const float*)d_in[8];
  const float* x_proj_w  = (const float*)d_in[9];
  const float* dt_w      = (const float*)d_in[10];
  const float* dt_b      = (const float*)d_in[11];
  const float* A_logs    = (const float*)d_in[12];
  const float* Ds_       = (const float*)d_in[13];
  const float* ong       = (const float*)d_in[14];
  const float* onb       = (const float*)d_in[15];
  const float* wout      = (const float*)d_in[16];
  float* out0 = (float*)d_out;
  float* out1 = out0 + 786432;
  float* ws = (float*)d_ws;
  float* XC   = ws;                  // 786432
  float* XT   = XC   + 786432;       // 786432
  float* Z    = XT   + 786432;       // 3145728  (B,HW,192)
  float* XPRE = Z    + 3145728;      // 3145728  dead after k_convx -> reused as Y
  float* XTT  = XPRE + 3145728;      // 6291456  (B,192,2,HW)
  float* KD   = XTT  + 6291456;      // 29184 (transposed: [i][m])
  float* XDBL = KD   + 29184;        // 2490368  (B,4,38,L)
  float* OUTY = XDBL + 2490368;      // 12582912 (B,4,192,L)
  float* T1   = OUTY + 12582912;     // 3145728
  float* T3   = T1   + 3145728;      // 3145728
  float* Sg   = T3   + 3145728;      // 11010048 floats (chain x 7*1024); pre-scan reused for XTNP/WB
  float* HEND = Sg   + 11010048;     // 196608   (8 x 24576)
  float* SEND = HEND + 196608;       // 12288    (8 x 1536)
  float* H0   = SEND + 12288;        // 196608   (8 x 24576)
  float* Y    = XPRE;                // reuse
  u16* XTNP = (u16*)Sg;              // 4,181,760 halfs (zero-padded NHWC bf16)
  u16* WB   = (u16*)(Sg + 4194304);  // 921,600 halfs (bf16 weights + kd tap)

  k_ln    <<<dim3(4096), dim3(256), 0, stream>>>(input0, input1, ln1_g, ln1_b, XC, XT, out1);
  k_inproj<<<dim3(256),  dim3(256), 0, stream>>>(XC, in_proj_w, XPRE, Z);
  k_convx <<<dim3(6144), dim3(256), 0, stream>>>(XPRE, conv2d_w, conv2d_b, XTT);
  k_convxt<<<dim3(6144), dim3(256), 0, stream>>>(XT, conv2dxt_w, conv2dxt_b, XTT);
  k_kd    <<<dim3(114),  dim3(256), 0, stream>>>(x_proj_w, KD);
  k_zero  <<<dim3(2432), dim3(256), 0, stream>>>((float4*)XDBL, 622592);
  k_zero  <<<dim3(2042), dim3(256), 0, stream>>>((float4*)XTNP, 522720);
  k_xtn   <<<dim3(64,6,4), dim3(256), 0, stream>>>(XTT, XTNP);
  k_wb    <<<dim3(3600), dim3(256), 0, stream>>>(x_proj_w, KD, WB);
  k_outn  <<<dim3(32,2,8), dim3(256), 0, stream>>>(XTNP, WB, XDBL);
  k_scan_a<<<dim3(48,4,16), dim3(64), 0, stream>>>(XDBL, XTT, dt_w, dt_b, A_logs, Ds_, OUTY, Sg, HEND, SEND);
  k_scan_b<<<dim3(96), dim3(256), 0, stream>>>(A_logs, HEND, SEND, H0);
  k_scan_c<<<dim3(8,7,8), dim3(128), 0, stream>>>(XDBL, A_logs, Sg, H0, OUTY);
  k_transp<<<dim3(1536), dim3(256), 0, stream>>>(OUTY, T1, T3);
  k_combine<<<dim3(128,2), dim3(256), 0, stream>>>(OUTY, T1, T3, Z, ong, onb, Y);
  k_outproj<<<dim3(256),  dim3(256), 0, stream>>>(Y, XC, wout, out0);
}

// Round 9
// 630.425 us; speedup vs baseline: 1.0558x; 1.0558x over previous
//
#include <hip/hip_runtime.h>
#include <math.h>

#define THETA 0.6f
typedef unsigned short u16;
typedef unsigned int u32;
typedef __attribute__((ext_vector_type(8))) short bf16x8;
typedef __attribute__((ext_vector_type(4))) float f32x4;

__device__ __forceinline__ float sigm(float x){ return 1.0f/(1.0f+__expf(-x)); }
__device__ __forceinline__ float siluf(float x){ return x*sigm(x); }
__device__ __forceinline__ float softplusf(float x){ return x>20.0f ? x : log1pf(__expf(x)); }
__device__ __forceinline__ u16 f2b(float x){
  u32 u = __float_as_uint(x);
  u32 r = (u + 0x7FFFu + ((u>>16)&1u)) >> 16;
  return (u16)r;
}
#define LOG2E 1.44269504f

// ---------------- K1: dual layernorm (rows of 96), one wave per row ----------------
__global__ __launch_bounds__(256) void k_ln(const float* __restrict__ in0, const float* __restrict__ in1,
     const float* __restrict__ g, const float* __restrict__ bb,
     float* __restrict__ xc, float* __restrict__ xt, float* __restrict__ out1){
  int wave = threadIdx.x>>6, lane = threadIdx.x&63;
  int row = blockIdx.x*4 + wave;           // 0..16383
  int which = row >= 8192;
  int r = which ? row - 8192 : row;
  const float* src = which ? in1 : in0;
  float v0 = src[(long)r*96 + lane];
  float v1 = (lane<32) ? src[(long)r*96 + 64 + lane] : 0.0f;
  float s = v0+v1, s2 = v0*v0+v1*v1;
  for (int m=1; m<64; m<<=1){ s += __shfl_xor(s, m); s2 += __shfl_xor(s2, m); }
  float mean = s*(1.0f/96.0f);
  float var = fmaxf(s2*(1.0f/96.0f) - mean*mean, 0.0f);
  float rstd = rsqrtf(var + 1e-6f);
  float y0 = (v0-mean)*rstd*g[lane] + bb[lane];
  float y1 = 0.f;
  if (lane<32) y1 = (v1-mean)*rstd*g[64+lane] + bb[64+lane];
  if (!which){
    xc[(long)r*96+lane] = y0;
    if (lane<32) xc[(long)r*96+64+lane] = y1;
  } else {
    xt[(long)r*96+lane] = y0; out1[(long)r*96+lane] = y0;
    if (lane<32){ xt[(long)r*96+64+lane] = y1; out1[(long)r*96+64+lane] = y1; }
  }
}

// ---------------- K2: xz = xc @ in_proj_w (8192x96 @ 96x384), 32-row tiles ----------------
__global__ __launch_bounds__(256) void k_inproj(const float* __restrict__ xc, const float* __restrict__ w,
     float* __restrict__ xpre, float* __restrict__ z){
  __shared__ __align__(16) float At[32*97];
  __shared__ __align__(16) float Bt[96*64];
  int tid = threadIdx.x; int tx = tid&15, ty = tid>>4;
  long rowbase = (long)blockIdx.x*32;
  for (int idx=tid; idx<32*96; idx+=256){ int r=idx/96, c=idx-r*96; At[r*97+c] = xc[(rowbase+r)*96+c]; }
  for (int nc=0; nc<6; ++nc){
    __syncthreads();
    for (int idx=tid; idx<96*64; idx+=256){ int kk=idx>>6, cc=idx&63; Bt[idx] = w[kk*384 + nc*64 + cc]; }
    __syncthreads();
    float acc[2][4] = {};
    for (int kk=0; kk<96; ++kk){
      float a0=At[(ty*2+0)*97+kk], a1=At[(ty*2+1)*97+kk];
      const float4 bv = *(const float4*)&Bt[kk*64 + tx*4];
      acc[0][0]+=a0*bv.x; acc[0][1]+=a0*bv.y; acc[0][2]+=a0*bv.z; acc[0][3]+=a0*bv.w;
      acc[1][0]+=a1*bv.x; acc[1][1]+=a1*bv.y; acc[1][2]+=a1*bv.z; acc[1][3]+=a1*bv.w;
    }
    for (int i=0;i<2;++i){
      long row = rowbase + ty*2 + i; int b = (int)(row>>12); int hw = (int)(row&4095);
      for (int j=0;j<4;++j){
        int n = nc*64 + tx*4 + j; float v = acc[i][j];
        if (n<192) xpre[((long)(b*192+n)<<12) + hw] = v;
        else z[row*192 + (n-192)] = v;
      }
    }
  }
}

// ---------------- K3a: depthwise 3x3 conv on x (NCHW) + silu ----------------
__global__ __launch_bounds__(256) void k_convx(const float* __restrict__ xpre, const float* __restrict__ wc,
     const float* __restrict__ bc, float* __restrict__ xtt){
  int idx = blockIdx.x*256 + threadIdx.x;  // < 2*192*4096
  int hw = idx & 4095; int d = (idx>>12)%192; int b = idx/(4096*192);
  int h = hw>>6, w = hw&63;
  float acc = bc[d];
  const float* src = xpre + ((long)(b*192+d)<<12);
  for (int dh=0; dh<3; ++dh){ int hh=h+dh-1; if (hh<0||hh>63) continue;
    for (int dw=0; dw<3; ++dw){ int ww=w+dw-1; if (ww<0||ww>63) continue;
      acc += wc[d*9+dh*3+dw]*src[hh*64+ww]; } }
  xtt[((long)(b*192+d)<<13) + hw] = siluf(acc);
}

// ---------------- K3b: grouped 3x3 conv on xt + silu ----------------
__global__ __launch_bounds__(256) void k_convxt(const float* __restrict__ xtn, const float* __restrict__ wc,
     const float* __restrict__ bc, float* __restrict__ xtt){
  int idx = blockIdx.x*256 + threadIdx.x;
  int hw = idx & 4095; int o = (idx>>12)%192; int b = idx/(4096*192);
  int h = hw>>6, w = hw&63; int ci = o>>1;
  float acc = bc[o];
  for (int dh=0; dh<3; ++dh){ int hh=h+dh-1; if (hh<0||hh>63) continue;
    for (int dw=0; dw<3; ++dw){ int ww=w+dw-1; if (ww<0||ww>63) continue;
      acc += wc[o*9+dh*3+dw]*xtn[((long)((b*64+hh)*64+ww))*96 + ci]; } }
  xtt[((long)(b*192+o)<<13) + 4096 + hw] = siluf(acc);
}

// ---------------- K4a: kd_t[i*152+m] ----------------
__global__ __launch_bounds__(256) void k_kd(const float* __restrict__ w, float* __restrict__ kdt){
  int idx = blockIdx.x*256 + threadIdx.x;
  if (idx >= 152*192) return;
  const float* p = w + (long)idx*18;
  float s = 0.f;
  #pragma unroll
  for (int j=0;j<18;++j) s += p[j];
  int m = idx/192, i = idx - m*192;
  kdt[i*152 + m] = s;
}

// ---------------- generic zero ----------------
__global__ __launch_bounds__(256) void k_zero(float4* __restrict__ p, int n4){
  int i = blockIdx.x*256 + threadIdx.x;
  if (i<n4) p[i] = make_float4(0.f,0.f,0.f,0.f);
}

// ---------------- K4x: xtt -> padded NHWC bf16 ----------------
__global__ __launch_bounds__(256) void k_xtn(const float* __restrict__ xtt, u16* __restrict__ xtnp){
  __shared__ float tl[64][33];
  int tid = threadIdx.x;
  int h = blockIdx.x; int cc = blockIdx.y;
  int b = blockIdx.z>>1, t = blockIdx.z&1;
  for (int i=tid; i<2048; i+=256){ int ch=i>>6, w=i&63;
    tl[w][ch] = xtt[((long)(b*192 + cc*32+ch)<<13) + t*4096 + h*64 + w]; }
  __syncthreads();
  long plane = (long)((b*2+t)*6+cc)*174240;
  uint4* dst = (uint4*)(xtnp + plane);
  for (int i=tid; i<320; i+=256){
    int w = i/5, chunk = i - (i/5)*5;
    uint4 v = {0u,0u,0u,0u};
    if (chunk<4){
      int c0 = chunk*8;
      v.x = (u32)f2b(tl[w][c0+0]) | ((u32)f2b(tl[w][c0+1])<<16);
      v.y = (u32)f2b(tl[w][c0+2]) | ((u32)f2b(tl[w][c0+3])<<16);
      v.z = (u32)f2b(tl[w][c0+4]) | ((u32)f2b(tl[w][c0+5])<<16);
      v.w = (u32)f2b(tl[w][c0+6]) | ((u32)f2b(tl[w][c0+7])<<16);
    }
    dst[((h+1)*66 + (w+1))*5 + chunk] = v;
  }
}

// ---------------- K4w: weights -> bf16 WB ----------------
__global__ __launch_bounds__(256) void k_wb(const float* __restrict__ xpw, const float* __restrict__ kdt,
     u16* __restrict__ wb){
  int idx = blockIdx.x*256 + threadIdx.x;
  if (idx >= 921600) return;
  int sl = idx%40; int rest = idx/40;
  int mm = rest%48; rest /= 48;
  int tap = rest%10; rest /= 10;
  int cc = rest%6; rest /= 6;
  int t = rest%2; int kg = rest/2;
  u16 v = 0;
  if (sl<32 && mm<38){
    int ch = cc*32+sl; int m = kg*38+mm;
    float f = (tap<9) ? xpw[(long)m*3456 + ch*18 + t*9 + tap] : kdt[ch*152 + m];
    v = f2b(f);
  }
  wb[idx] = v;
}

// ---------------- K4b: x_dbl += out_n - theta*out_d via bf16 MFMA ----------------
__global__ __launch_bounds__(256) void k_outn(const u16* __restrict__ xtnp, const u16* __restrict__ wb,
     float* __restrict__ xdbl){
  __shared__ __align__(16) u16 Bl[264*40];
  __shared__ __align__(16) u16 Al[10*48*40];
  int tid = threadIdx.x, wv = tid>>6, lane = tid&63;
  int n = lane&15, kq = lane>>4;
  int hp = blockIdx.x, b = blockIdx.y;
  int kg = blockIdx.z>>1, t = blockIdx.z&1;
  f32x4 accN[2][3], accD[2][3];
  #pragma unroll
  for (int q=0;q<2;++q)
    #pragma unroll
    for (int mt=0;mt<3;++mt){ accN[q][mt] = (f32x4){0.f,0.f,0.f,0.f}; accD[q][mt] = (f32x4){0.f,0.f,0.f,0.f}; }

  for (int cc=0; cc<6; ++cc){
    const float4* srcB = (const float4*)(xtnp + (long)((b*2+t)*6+cc)*174240 + (long)hp*132*40);
    const float4* srcA = (const float4*)(wb + (long)((kg*2+t)*6+cc)*19200);
    float4 tb[6]; float4 ta[10];
    #pragma unroll
    for (int q=0;q<6;++q){ int ix = tid + q*256; if (ix<1320) tb[q] = srcB[ix]; }
    #pragma unroll
    for (int q=0;q<10;++q){ int ix = tid + q*256; if (ix<2400) ta[q] = srcA[ix]; }
    __syncthreads();
    #pragma unroll
    for (int q=0;q<6;++q){ int ix = tid + q*256; if (ix<1320) ((float4*)Bl)[ix] = tb[q]; }
    #pragma unroll
    for (int q=0;q<10;++q){ int ix = tid + q*256; if (ix<2400) ((float4*)Al)[ix] = ta[q]; }
    __syncthreads();
    #pragma unroll
    for (int tap=0; tap<10; ++tap){
      int dh = (tap<9) ? tap/3 : 1;
      int dw = (tap<9) ? (tap - (tap/3)*3) : 1;
      bf16x8 a0 = *(const bf16x8*)&Al[(tap*48 +  0 + n)*40 + kq*8];
      bf16x8 a1 = *(const bf16x8*)&Al[(tap*48 + 16 + n)*40 + kq*8];
      bf16x8 a2 = *(const bf16x8*)&Al[(tap*48 + 32 + n)*40 + kq*8];
      bf16x8 b0 = *(const bf16x8*)&Bl[((0+dh)*66 + wv*16 + dw + n)*40 + kq*8];
      bf16x8 b1 = *(const bf16x8*)&Bl[((1+dh)*66 + wv*16 + dw + n)*40 + kq*8];
      if (tap<9){
        accN[0][0] = __builtin_amdgcn_mfma_f32_16x16x32_bf16(a0, b0, accN[0][0], 0,0,0);
        accN[0][1] = __builtin_amdgcn_mfma_f32_16x16x32_bf16(a1, b0, accN[0][1], 0,0,0);
        accN[0][2] = __builtin_amdgcn_mfma_f32_16x16x32_bf16(a2, b0, accN[0][2], 0,0,0);
        accN[1][0] = __builtin_amdgcn_mfma_f32_16x16x32_bf16(a0, b1, accN[1][0], 0,0,0);
        accN[1][1] = __builtin_amdgcn_mfma_f32_16x16x32_bf16(a1, b1, accN[1][1], 0,0,0);
        accN[1][2] = __builtin_amdgcn_mfma_f32_16x16x32_bf16(a2, b1, accN[1][2], 0,0,0);
      } else {
        accD[0][0] = __builtin_amdgcn_mfma_f32_16x16x32_bf16(a0, b0, accD[0][0], 0,0,0);
        accD[0][1] = __builtin_amdgcn_mfma_f32_16x16x32_bf16(a1, b0, accD[0][1], 0,0,0);
        accD[0][2] = __builtin_amdgcn_mfma_f32_16x16x32_bf16(a2, b0, accD[0][2], 0,0,0);
        accD[1][0] = __builtin_amdgcn_mfma_f32_16x16x32_bf16(a0, b1, accD[1][0], 0,0,0);
        accD[1][1] = __builtin_amdgcn_mfma_f32_16x16x32_bf16(a1, b1, accD[1][1], 0,0,0);
        accD[1][2] = __builtin_amdgcn_mfma_f32_16x16x32_bf16(a2, b1, accD[1][2], 0,0,0);
      }
    }
    __syncthreads();
  }
  #pragma unroll
  for (int q=0;q<2;++q){
    int hw = (hp*2+q)*64 + wv*16 + n;
    #pragma unroll
    for (int mt=0; mt<3; ++mt){
      #pragma unroll
      for (int r=0;r<4;++r){
        int m = mt*16 + kq*4 + r;
        if (m<38){
          long base = ((long)((b*4+kg)*38+m)<<13) + hw;
          float vN = accN[q][mt][r];
          float vD = accD[q][mt][r];
          unsafeAtomicAdd(&xdbl[base + t*4096], vN - THETA*vD);
          unsafeAtomicAdd(&xdbl[base + (1-t)*4096], vN);
        }
      }
    }
  }
}

// ---------------- K5: delta precompute. 1 wave per (chain, 512-chunk). ----------------
// Writes: DDU (bf16 delta | bf16 delta*u packed u32, overlaid on OUTY), S (per-chunk cumsum), send.
__global__ __launch_bounds__(256) void k_delta(const float* __restrict__ xdbl, const float* __restrict__ xtt,
    const float* __restrict__ dt_w, const float* __restrict__ dt_b,
    u32* __restrict__ ddu, float* __restrict__ S, float* __restrict__ send){
  int wv = threadIdx.x>>6, lane = threadIdx.x&63;
  int gw = blockIdx.x*4 + wv;                 // < 24576
  int chunk = gw & 15; int chain = gw >> 4;   // chain = (b*4+k)*192 + d
  int d = chain % 192; int kb = chain/192; int k = kb & 3; int b = kb >> 2;
  bool rev = (k&1);
  const float* xrow = xdbl + ((long)kb*38<<13);
  float dtw[6];
  #pragma unroll
  for (int r=0;r<6;++r) dtw[r] = dt_w[(k*192+d)*6 + r];
  float dtb = dt_b[k*192+d];
  int l0 = chunk*512 + lane*8;
  // load dts rows
  float dts[6][8];
  #pragma unroll
  for (int r=0;r<6;++r){
    *(float4*)&dts[r][0] = *(const float4*)&xrow[((long)r<<13) + l0];
    *(float4*)&dts[r][4] = *(const float4*)&xrow[((long)r<<13) + l0 + 4];
  }
  // load u (rev-aware)
  float u8[8];
  {
    const float* ub = xtt + ((long)(b*192+d)<<13);
    float tmp[8];
    long base = rev ? (long)(8191 - l0 - 7) : (long)l0;
    *(float4*)&tmp[0] = *(const float4*)&ub[base];
    *(float4*)&tmp[4] = *(const float4*)&ub[base+4];
    #pragma unroll
    for (int j=0;j<8;++j) u8[j] = rev ? tmp[7-j] : tmp[j];
  }
  // delta + local prefix
  float del[8], pre[8]; float run = 0.f;
  #pragma unroll
  for (int j=0;j<8;++j){
    float s = dtb;
    #pragma unroll
    for (int r=0;r<6;++r) s += dts[r][j]*dtw[r];
    float dv = softplusf(s);
    del[j] = dv; run += dv; pre[j] = run;
  }
  // wave-wide prefix of lane totals (64-lane inclusive)
  float p = run;
  #pragma unroll
  for (int off=1; off<64; off<<=1){
    float t = __shfl_up(p, off);
    if (lane>=off) p += t;
  }
  float excl = p - run;
  // write S and packed DDU
  {
    float so[8]; u32 po[8];
    #pragma unroll
    for (int j=0;j<8;++j){
      so[j] = excl + pre[j];
      po[j] = ((u32)f2b(del[j])<<16) | (u32)f2b(del[j]*u8[j]);
    }
    float* Sp = S + (long)chain*8192 + l0;
    *(float4*)&Sp[0] = *(float4*)&so[0];
    *(float4*)&Sp[4] = *(float4*)&so[4];
    u32* Dp = ddu + (long)chain*8192 + l0;
    *(uint4*)&Dp[0] = *(uint4*)&po[0];
    *(uint4*)&Dp[4] = *(uint4*)&po[4];
  }
  if (lane==63) send[chunk*1536 + chain] = p;
}

// ---------------- K6a: lean chunked scan. C=16 chunks of 512, ~8.5KB LDS ----------------
__global__ __launch_bounds__(64) void k_scan_a(const float* __restrict__ xdbl, const float* __restrict__ xtt,
    const u32* __restrict__ ddu, const float* __restrict__ A_logs, const float* __restrict__ Ds,
    float* __restrict__ outy, float* __restrict__ hend){
  __shared__ u32 ddu2[4][32];
  __shared__ float uls[4][33];
  __shared__ __align__(16) float2 BCl[16][17];
  __shared__ __align__(16) float P[4][328];
  __shared__ float Dl[4];
  int tid = threadIdx.x; int n = tid&15; int dl = tid>>4;
  int th = tid&31, hf = tid>>5;
  int dg = blockIdx.x; int k = blockIdx.y; int zz = blockIdx.z;
  int b = zz>>4; int c = zz&15;
  int dbase = dg*4; bool rev = (k&1);
  if (tid<4) Dl[tid] = Ds[k*192 + dbase + tid];
  float Aval2 = -__expf(A_logs[(k*192 + dbase + dl)*16 + n]) * LOG2E;
  long chainb = (long)(b*4+k)*192 + dbase;
  const float* xrow = xdbl + ((long)(b*4+k)*38<<13);
  float h = 0.f;
  int nr = tid>>2, t4 = (tid&3)*4;
  __syncthreads();
  for (int ph=0; ph<16; ++ph){
    int l0 = c*512 + ph*32;
    // stage ddu (dwordx2 per lane) and u
    {
      const u32* src = ddu + (chainb + (tid>>4))*8192 + l0 + (tid&15)*2;
      uint2 v = *(const uint2*)src;
      *(uint2*)&ddu2[tid>>4][(tid&15)*2] = v;
    }
    #pragma unroll
    for (int q=0;q<2;++q){ int j = q*2+hf;
      long li = rev ? (long)(8191-(l0+th)) : (long)(l0+th);
      uls[j][th] = xtt[((long)(b*192 + dbase + j)<<13) + li];
    }
    __syncthreads();
    #pragma unroll
    for (int h2=0; h2<2; ++h2){
      int lh = l0 + h2*16;
      // stage B/C half-tile (16 n x 16 t, swizzled)
      {
        float4 vB = *(const float4*)&xrow[((long)(6+nr)<<13) + lh + t4];
        float4 vC = *(const float4*)&xrow[((long)(22+nr)<<13) + lh + t4];
        const float* pb = &vB.x; const float* pc = &vC.x;
        #pragma unroll
        for (int e=0;e<4;++e){
          int t = t4+e;
          BCl[t][(nr+t)&15] = make_float2(pb[e], pc[e]);
        }
      }
      __syncthreads();
      #pragma unroll
      for (int s=0; s<16; ++s){
        u32 dd = ddu2[dl][h2*16+s];
        float del = __uint_as_float(dd & 0xFFFF0000u);
        float du  = __uint_as_float(dd << 16);
        float2 bc = BCl[s][(n+s)&15];
        float a = exp2f(del * Aval2);
        h = fmaf(a, h, du * bc.x);
        P[dl][s*20+n] = h * bc.y;
      }
      __syncthreads();
      {
        int j = tid>>4, tq = tid&15;
        const float4* pr = (const float4*)&P[j][tq*20];
        float4 q0=pr[0], q1=pr[1], q2=pr[2], q3=pr[3];
        float y = ((q0.x+q0.y)+(q0.z+q0.w)) + ((q1.x+q1.y)+(q1.z+q1.w))
                + ((q2.x+q2.y)+(q2.z+q2.w)) + ((q3.x+q3.y)+(q3.z+q3.w));
        int tt = h2*16 + tq;
        outy[((chainb+j)<<13) + l0 + tt] = y + Dl[j]*uls[j][tt];
      }
      __syncthreads();
    }
  }
  long chain = chainb + dl;
  hend[c*24576 + chain*16 + n] = h;
}

// ---------------- K6b: carry propagation across the 16 chunks ----------------
__global__ __launch_bounds__(256) void k_scan_b(const float* __restrict__ A_logs,
    const float* __restrict__ hend, const float* __restrict__ send, float* __restrict__ h0g){
  int idx = blockIdx.x*256 + threadIdx.x;   // < 24576
  int chain = idx>>4, n = idx&15;
  int d = chain%192; int kk = (chain/192)&3;
  float A2 = -__expf(A_logs[(kk*192+d)*16+n]) * LOG2E;
  float h0 = 0.f;
  #pragma unroll
  for (int c=0;c<15;++c){
    h0 = exp2f(A2*send[c*1536+chain])*h0 + hend[c*24576+idx];
    h0g[(c+1)*24576 + idx] = h0;
  }
}

// ---------------- K6c: fix-up for chunks 1..15 ----------------
__global__ __launch_bounds__(128) void k_scan_c(const float* __restrict__ xdbl,
    const float* __restrict__ A_logs, const float* __restrict__ S, const float* __restrict__ h0g,
    float* __restrict__ outy){
  __shared__ float Cl[16][128];
  __shared__ float h0l[192][16];
  __shared__ float Al[192][16];
  int tid = threadIdx.x;
  int tt0 = blockIdx.x*128; int c = blockIdx.y+1; int z = blockIdx.z;
  int b = z>>2, k = z&3;
  const float* xrow = xdbl + ((long)((b*4+k)*38)<<13);
  for (int idx=tid; idx<2048; idx+=128){
    int nn = idx>>7, t = idx&127;
    Cl[nn][t] = xrow[((long)(22+nn)<<13) + c*512 + tt0 + t];
  }
  for (int idx=tid; idx<3072; idx+=128){
    int d = idx>>4, nn = idx&15;
    h0l[d][nn] = h0g[c*24576 + ((b*4+k)*192+d)*16 + nn];
    Al[d][nn]  = -__expf(A_logs[(k*192+d)*16+nn]) * LOG2E;
  }
  __syncthreads();
  int t = tid;
  for (int d=0; d<192; ++d){
    long chain = (long)((b*4+k)*192 + d);
    float Sv = S[chain*8192 + c*512 + tt0 + t];
    float acc = 0.f;
    #pragma unroll
    for (int nn=0; nn<16; ++nn) acc += Cl[nn][t]*exp2f(Al[d][nn]*Sv)*h0l[d][nn];
    long yi = (chain<<13) + c*512 + tt0 + t;
    outy[yi] += acc;
  }
}

// ---------------- K7a: per-frame 64x64 spatial transpose ----------------
__global__ __launch_bounds__(256) void k_transp(const float* __restrict__ outy, float* __restrict__ T1,
     float* __restrict__ T3){
  __shared__ float tl[64*65];
  int idx = blockIdx.x;         // < 1536
  int t = idx&1; int q = idx>>1; int d = q%192; int r2 = q/192; int ksel = r2&1; int b = r2>>1;
  int k = ksel ? 3 : 1;
  const float* src = outy + ((long)((b*4+k)*192 + d)<<13) + t*4096;
  float* dst = (ksel ? T3 : T1) + ((long)(b*192 + d)<<13) + t*4096;
  int tid = threadIdx.x;
  for (int i=tid; i<4096; i+=256){ int r=i>>6, c=i&63; tl[c*65+r] = src[i]; }
  __syncthreads();
  for (int i=tid; i<4096; i+=256){ int r=i>>6, c=i&63; dst[i] = tl[r*65+c]; }
}

// ---------------- K7b: 8-term combine + out-LN + silu(z) gate -> Y ----------------
__global__ __launch_bounds__(256) void k_combine(const float* __restrict__ outy,
    const float* __restrict__ T1, const float* __restrict__ T3,
    const float* __restrict__ z, const float* __restrict__ ong, const float* __restrict__ onb,
    float* __restrict__ Y){
  __shared__ float yt[32][193];
  __shared__ float redl[32][8][2];
  __shared__ float stats[32][2];
  int tid = threadIdx.x;
  int tx = tid&31, ty = tid>>5;
  int b = blockIdx.y;
  long pg = (long)(blockIdx.x&127)*32 + tx;
  float s = 0.f, s2 = 0.f;
  #pragma unroll 4
  for (int dc=0; dc<24; ++dc){
    int d = dc*8 + ty;
    const float* r0 = outy + ((long)(b*768 + d)<<13);
    const float* r2 = outy + ((long)(b*768 + 384 + d)<<13);
    const float* t1 = T1 + ((long)(b*192 + d)<<13);
    const float* t3 = T3 + ((long)(b*192 + d)<<13);
    float v = r0[pg] + r0[4096+pg] + r2[8191-pg] + r2[4095-pg]
            + t1[pg] + t1[4096+pg] + t3[8191-pg] + t3[4095-pg];
    yt[tx][d] = v; s += v; s2 += v*v;
  }
  redl[tx][ty][0] = s; redl[tx][ty][1] = s2;
  __syncthreads();
  if (tid<32){
    float Sx=0.f, S2=0.f;
    #pragma unroll
    for (int g=0; g<8; ++g){ Sx += redl[tid][g][0]; S2 += redl[tid][g][1]; }
    float m = Sx*(1.f/192.f);
    float var = fmaxf(S2*(1.f/192.f) - m*m, 0.f);
    stats[tid][0] = m; stats[tid][1] = rsqrtf(var + 1e-5f);
  }
  __syncthreads();
  long rowbase = (long)b*4096 + (blockIdx.x&127)*32;
  #pragma unroll 4
  for (int idx=tid; idx<32*192; idx+=256){
    int r = idx/192, d = idx - r*192;
    float v = (yt[r][d] - stats[r][0])*stats[r][1]*ong[d] + onb[d];
    float zv = z[(rowbase+r)*192 + d];
    Y[(rowbase+r)*192 + d] = v*(zv*sigm(zv));
  }
}

// ---------------- K7c: out0 = xc + Y @ wout ----------------
__global__ __launch_bounds__(256) void k_outproj(const float* __restrict__ Y,
    const float* __restrict__ xc, const float* __restrict__ wout, float* __restrict__ out0){
  __shared__ float Yl[32][193];
  __shared__ __align__(16) float Wl[48*96];
  int tid = threadIdx.x;
  int r = tid>>3, cq = tid&7;
  long rowbase = (long)blockIdx.x*32;
  for (int idx=tid; idx<32*192; idx+=256){
    int rr = idx/192, d = idx - rr*192;
    Yl[rr][d] = Y[(rowbase+rr)*192 + d];
  }
  float acc[12] = {};
  for (int db=0; db<192; db+=48){
    __syncthreads();
    for (int idx=tid; idx<48*96; idx+=256) Wl[idx] = wout[db*96 + idx];
    __syncthreads();
    #pragma unroll 4
    for (int dd=0; dd<48; ++dd){
      float yv = Yl[r][db+dd];
      const float4* wr = (const float4*)&Wl[dd*96 + cq*12];
      float4 w0=wr[0], w1=wr[1], w2=wr[2];
      acc[0]+=yv*w0.x; acc[1]+=yv*w0.y; acc[2]+=yv*w0.z;  acc[3]+=yv*w0.w;
      acc[4]+=yv*w1.x; acc[5]+=yv*w1.y; acc[6]+=yv*w1.z;  acc[7]+=yv*w1.w;
      acc[8]+=yv*w2.x; acc[9]+=yv*w2.y; acc[10]+=yv*w2.z; acc[11]+=yv*w2.w;
    }
  }
  long ob = (rowbase + r)*96 + cq*12;
  #pragma unroll
  for (int j=0;j<12;++j) out0[ob+j] = xc[ob+j] + acc[j];
}

extern "C" void kernel_launch(void* const* d_in, const int* in_sizes, int n_in,
                              void* d_out, int out_size, void* d_ws, size_t ws_size,
                              hipStream_t stream) {
  const float* input0    = (const float*)d_in[0];
  const float* input1    = (const float*)d_in[1];
  const float* ln1_g     = (const float*)d_in[2];
  const float* ln1_b     = (const float*)d_in[3];
  const float* in_proj_w = (const float*)d_in[4];
  const float* conv2d_w  = (const float*)d_in[5];
  const float* conv2d_b  = (const float*)d_in[6];
  const float* conv2dxt_w= (const float*)d_in[7];
  const float* conv2dxt_b= (const float*)d_in[8];
  const float* x_proj_w  = (const float*)d_in[9];
  const float* dt_w      = (const float*)d_in[10];
  const float* dt_b      = (const float*)d_in[11];
  const float* A_logs    = (const float*)d_in[12];
  const float* Ds_       = (const float*)d_in[13];
  const float* ong       = (const float*)d_in[14];
  const float* onb       = (const float*)d_in[15];
  const float* wout      = (const float*)d_in[16];
  float* out0 = (float*)d_out;
  float* out1 = out0 + 786432;
  float* ws = (float*)d_ws;
  float* XC   = ws;                  // 786432
  float* XT   = XC   + 786432;       // 786432
  float* Z    = XT   + 786432;       // 3145728
  float* XPRE = Z    + 3145728;      // 3145728  dead after k_convx -> reused as Y
  float* XTT  = XPRE + 3145728;      // 6291456
  float* KD   = XTT  + 6291456;      // 29184
  float* XDBL = KD   + 29184;        // 2490368
  float* OUTY = XDBL + 2490368;      // 12582912; doubles as packed DDU (u32) before scan_a writes
  float* T1   = OUTY + 12582912;     // 3145728
  float* T3   = T1   + 3145728;      // 3145728
  float* SCR  = T3   + 3145728;      // 4655104 region for XTNP/WB (bf16)
  float* HEND = SCR  + 4655104;      // 393216 (16 x 24576)
  float* SEND = HEND + 393216;       // 24576  (16 x 1536)
  float* H0   = SEND + 24576;        // 393216
  float* Sarr = H0   + 393216;       // 12582912 (chain x 8192 per-chunk cumsum)
  float* Y    = XPRE;                // reuse
  u16* XTNP = (u16*)SCR;             // 4,181,760 halfs
  u16* WB   = (u16*)(SCR + 4194304); // 921,600 halfs
  u32* DDU  = (u32*)OUTY;            // packed (delta|delta*u) bf16x2

  k_ln    <<<dim3(4096), dim3(256), 0, stream>>>(input0, input1, ln1_g, ln1_b, XC, XT, out1);
  k_inproj<<<dim3(256),  dim3(256), 0, stream>>>(XC, in_proj_w, XPRE, Z);
  k_convx <<<dim3(6144), dim3(256), 0, stream>>>(XPRE, conv2d_w, conv2d_b, XTT);
  k_convxt<<<dim3(6144), dim3(256), 0, stream>>>(XT, conv2dxt_w, conv2dxt_b, XTT);
  k_kd    <<<dim3(114),  dim3(256), 0, stream>>>(x_proj_w, KD);
  k_zero  <<<dim3(2432), dim3(256), 0, stream>>>((float4*)XDBL, 622592);
  k_zero  <<<dim3(2042), dim3(256), 0, stream>>>((float4*)XTNP, 522720);
  k_xtn   <<<dim3(64,6,4), dim3(256), 0, stream>>>(XTT, XTNP);
  k_wb    <<<dim3(3600), dim3(256), 0, stream>>>(x_proj_w, KD, WB);
  k_outn  <<<dim3(32,2,8), dim3(256), 0, stream>>>(XTNP, WB, XDBL);
  k_delta <<<dim3(6144), dim3(256), 0, stream>>>(XDBL, XTT, dt_w, dt_b, DDU, Sarr, SEND);
  k_scan_a<<<dim3(48,4,32), dim3(64), 0, stream>>>(XDBL, XTT, DDU, A_logs, Ds_, OUTY, HEND);
  k_scan_b<<<dim3(96), dim3(256), 0, stream>>>(A_logs, HEND, SEND, H0);
  k_scan_c<<<dim3(4,15,8), dim3(128), 0, stream>>>(XDBL, A_logs, Sarr, H0, OUTY);
  k_transp<<<dim3(1536), dim3(256), 0, stream>>>(OUTY, T1, T3);
  k_combine<<<dim3(128,2), dim3(256), 0, stream>>>(OUTY, T1, T3, Z, ong, onb, Y);
  k_outproj<<<dim3(256),  dim3(256), 0, stream>>>(Y, XC, wout, out0);
}

// Round 10
// 531.633 us; speedup vs baseline: 1.2520x; 1.1858x over previous
//
#include <hip/hip_runtime.h>
#include <math.h>

#define THETA 0.6f
typedef unsigned short u16;
typedef unsigned int u32;
typedef __attribute__((ext_vector_type(8))) short bf16x8;
typedef __attribute__((ext_vector_type(4))) float f32x4;

__device__ __forceinline__ float sigm(float x){ return 1.0f/(1.0f+__expf(-x)); }
__device__ __forceinline__ float siluf(float x){ return x*sigm(x); }
__device__ __forceinline__ float softplusf(float x){ return x>20.0f ? x : log1pf(__expf(x)); }
__device__ __forceinline__ u16 f2b(float x){
  u32 u = __float_as_uint(x);
  u32 r = (u + 0x7FFFu + ((u>>16)&1u)) >> 16;
  return (u16)r;
}
#define LOG2E 1.44269504f

// ---------------- K1: dual layernorm (rows of 96), one wave per row ----------------
__global__ __launch_bounds__(256) void k_ln(const float* __restrict__ in0, const float* __restrict__ in1,
     const float* __restrict__ g, const float* __restrict__ bb,
     float* __restrict__ xc, float* __restrict__ xt, float* __restrict__ out1){
  int wave = threadIdx.x>>6, lane = threadIdx.x&63;
  int row = blockIdx.x*4 + wave;           // 0..16383
  int which = row >= 8192;
  int r = which ? row - 8192 : row;
  const float* src = which ? in1 : in0;
  float v0 = src[(long)r*96 + lane];
  float v1 = (lane<32) ? src[(long)r*96 + 64 + lane] : 0.0f;
  float s = v0+v1, s2 = v0*v0+v1*v1;
  for (int m=1; m<64; m<<=1){ s += __shfl_xor(s, m); s2 += __shfl_xor(s2, m); }
  float mean = s*(1.0f/96.0f);
  float var = fmaxf(s2*(1.0f/96.0f) - mean*mean, 0.0f);
  float rstd = rsqrtf(var + 1e-6f);
  float y0 = (v0-mean)*rstd*g[lane] + bb[lane];
  float y1 = 0.f;
  if (lane<32) y1 = (v1-mean)*rstd*g[64+lane] + bb[64+lane];
  if (!which){
    xc[(long)r*96+lane] = y0;
    if (lane<32) xc[(long)r*96+64+lane] = y1;
  } else {
    xt[(long)r*96+lane] = y0; out1[(long)r*96+lane] = y0;
    if (lane<32){ xt[(long)r*96+64+lane] = y1; out1[(long)r*96+64+lane] = y1; }
  }
}

// ---------------- K2: xz = xc @ in_proj_w (8192x96 @ 96x384), 32-row tiles ----------------
__global__ __launch_bounds__(256) void k_inproj(const float* __restrict__ xc, const float* __restrict__ w,
     float* __restrict__ xpre, float* __restrict__ z){
  __shared__ __align__(16) float At[32*97];
  __shared__ __align__(16) float Bt[96*64];
  int tid = threadIdx.x; int tx = tid&15, ty = tid>>4;
  long rowbase = (long)blockIdx.x*32;
  for (int idx=tid; idx<32*96; idx+=256){ int r=idx/96, c=idx-r*96; At[r*97+c] = xc[(rowbase+r)*96+c]; }
  for (int nc=0; nc<6; ++nc){
    __syncthreads();
    for (int idx=tid; idx<96*64; idx+=256){ int kk=idx>>6, cc=idx&63; Bt[idx] = w[kk*384 + nc*64 + cc]; }
    __syncthreads();
    float acc[2][4] = {};
    for (int kk=0; kk<96; ++kk){
      float a0=At[(ty*2+0)*97+kk], a1=At[(ty*2+1)*97+kk];
      const float4 bv = *(const float4*)&Bt[kk*64 + tx*4];
      acc[0][0]+=a0*bv.x; acc[0][1]+=a0*bv.y; acc[0][2]+=a0*bv.z; acc[0][3]+=a0*bv.w;
      acc[1][0]+=a1*bv.x; acc[1][1]+=a1*bv.y; acc[1][2]+=a1*bv.z; acc[1][3]+=a1*bv.w;
    }
    for (int i=0;i<2;++i){
      long row = rowbase + ty*2 + i; int b = (int)(row>>12); int hw = (int)(row&4095);
      for (int j=0;j<4;++j){
        int n = nc*64 + tx*4 + j; float v = acc[i][j];
        if (n<192) xpre[((long)(b*192+n)<<12) + hw] = v;
        else z[row*192 + (n-192)] = v;
      }
    }
  }
}

// ---------------- K3a: depthwise 3x3 conv on x (NCHW) + silu ----------------
__global__ __launch_bounds__(256) void k_convx(const float* __restrict__ xpre, const float* __restrict__ wc,
     const float* __restrict__ bc, float* __restrict__ xtt){
  int idx = blockIdx.x*256 + threadIdx.x;  // < 2*192*4096
  int hw = idx & 4095; int d = (idx>>12)%192; int b = idx/(4096*192);
  int h = hw>>6, w = hw&63;
  float acc = bc[d];
  const float* src = xpre + ((long)(b*192+d)<<12);
  for (int dh=0; dh<3; ++dh){ int hh=h+dh-1; if (hh<0||hh>63) continue;
    for (int dw=0; dw<3; ++dw){ int ww=w+dw-1; if (ww<0||ww>63) continue;
      acc += wc[d*9+dh*3+dw]*src[hh*64+ww]; } }
  xtt[((long)(b*192+d)<<13) + hw] = siluf(acc);
}

// ---------------- K3b: grouped 3x3 conv on xt + silu ----------------
__global__ __launch_bounds__(256) void k_convxt(const float* __restrict__ xtn, const float* __restrict__ wc,
     const float* __restrict__ bc, float* __restrict__ xtt){
  int idx = blockIdx.x*256 + threadIdx.x;
  int hw = idx & 4095; int o = (idx>>12)%192; int b = idx/(4096*192);
  int h = hw>>6, w = hw&63; int ci = o>>1;
  float acc = bc[o];
  for (int dh=0; dh<3; ++dh){ int hh=h+dh-1; if (hh<0||hh>63) continue;
    for (int dw=0; dw<3; ++dw){ int ww=w+dw-1; if (ww<0||ww>63) continue;
      acc += wc[o*9+dh*3+dw]*xtn[((long)((b*64+hh)*64+ww))*96 + ci]; } }
  xtt[((long)(b*192+o)<<13) + 4096 + hw] = siluf(acc);
}

// ---------------- K4a: kd_t[i*152+m] ----------------
__global__ __launch_bounds__(256) void k_kd(const float* __restrict__ w, float* __restrict__ kdt){
  int idx = blockIdx.x*256 + threadIdx.x;
  if (idx >= 152*192) return;
  const float* p = w + (long)idx*18;
  float s = 0.f;
  #pragma unroll
  for (int j=0;j<18;++j) s += p[j];
  int m = idx/192, i = idx - m*192;
  kdt[i*152 + m] = s;
}

// ---------------- generic zero ----------------
__global__ __launch_bounds__(256) void k_zero(float4* __restrict__ p, int n4){
  int i = blockIdx.x*256 + threadIdx.x;
  if (i<n4) p[i] = make_float4(0.f,0.f,0.f,0.f);
}

// ---------------- K4x: xtt -> padded NHWC bf16 ----------------
__global__ __launch_bounds__(256) void k_xtn(const float* __restrict__ xtt, u16* __restrict__ xtnp){
  __shared__ float tl[64][33];
  int tid = threadIdx.x;
  int h = blockIdx.x; int cc = blockIdx.y;
  int b = blockIdx.z>>1, t = blockIdx.z&1;
  for (int i=tid; i<2048; i+=256){ int ch=i>>6, w=i&63;
    tl[w][ch] = xtt[((long)(b*192 + cc*32+ch)<<13) + t*4096 + h*64 + w]; }
  __syncthreads();
  long plane = (long)((b*2+t)*6+cc)*174240;
  uint4* dst = (uint4*)(xtnp + plane);
  for (int i=tid; i<320; i+=256){
    int w = i/5, chunk = i - (i/5)*5;
    uint4 v = {0u,0u,0u,0u};
    if (chunk<4){
      int c0 = chunk*8;
      v.x = (u32)f2b(tl[w][c0+0]) | ((u32)f2b(tl[w][c0+1])<<16);
      v.y = (u32)f2b(tl[w][c0+2]) | ((u32)f2b(tl[w][c0+3])<<16);
      v.z = (u32)f2b(tl[w][c0+4]) | ((u32)f2b(tl[w][c0+5])<<16);
      v.w = (u32)f2b(tl[w][c0+6]) | ((u32)f2b(tl[w][c0+7])<<16);
    }
    dst[((h+1)*66 + (w+1))*5 + chunk] = v;
  }
}

// ---------------- K4w: weights -> bf16 WB ----------------
__global__ __launch_bounds__(256) void k_wb(const float* __restrict__ xpw, const float* __restrict__ kdt,
     u16* __restrict__ wb){
  int idx = blockIdx.x*256 + threadIdx.x;
  if (idx >= 921600) return;
  int sl = idx%40; int rest = idx/40;
  int mm = rest%48; rest /= 48;
  int tap = rest%10; rest /= 10;
  int cc = rest%6; rest /= 6;
  int t = rest%2; int kg = rest/2;
  u16 v = 0;
  if (sl<32 && mm<38){
    int ch = cc*32+sl; int m = kg*38+mm;
    float f = (tap<9) ? xpw[(long)m*3456 + ch*18 + t*9 + tap] : kdt[ch*152 + m];
    v = f2b(f);
  }
  wb[idx] = v;
}

// ---------------- K4b: x_dbl = out_n - theta*out_d via bf16 MFMA; t folded inside, plain stores ----------------
// grid (32 h-pairs, 2 b, 4 kg); block 256 = 4 waves; M=48 x N=128 tile.
__global__ __launch_bounds__(256) void k_outn(const u16* __restrict__ xtnp, const u16* __restrict__ wb,
     float* __restrict__ xdbl){
  __shared__ __align__(16) u16 Bl[264*40];     // 21120 B
  __shared__ __align__(16) u16 Al[10*48*40];   // 38400 B
  int tid = threadIdx.x, wv = tid>>6, lane = tid&63;
  int n = lane&15, kq = lane>>4;
  int hp = blockIdx.x, b = blockIdx.y;
  int kg = blockIdx.z;
  f32x4 accN[2][3], accD[2][2][3];
  #pragma unroll
  for (int q=0;q<2;++q)
    #pragma unroll
    for (int mt=0;mt<3;++mt){
      accN[q][mt] = (f32x4){0.f,0.f,0.f,0.f};
      accD[0][q][mt] = (f32x4){0.f,0.f,0.f,0.f};
      accD[1][q][mt] = (f32x4){0.f,0.f,0.f,0.f};
    }

  for (int t=0;t<2;++t){
    for (int cc=0; cc<6; ++cc){
      const float4* srcB = (const float4*)(xtnp + (long)((b*2+t)*6+cc)*174240 + (long)hp*132*40);
      const float4* srcA = (const float4*)(wb + (long)((kg*2+t)*6+cc)*19200);
      float4 tb[6]; float4 ta[10];
      #pragma unroll
      for (int q=0;q<6;++q){ int ix = tid + q*256; if (ix<1320) tb[q] = srcB[ix]; }
      #pragma unroll
      for (int q=0;q<10;++q){ int ix = tid + q*256; if (ix<2400) ta[q] = srcA[ix]; }
      __syncthreads();
      #pragma unroll
      for (int q=0;q<6;++q){ int ix = tid + q*256; if (ix<1320) ((float4*)Bl)[ix] = tb[q]; }
      #pragma unroll
      for (int q=0;q<10;++q){ int ix = tid + q*256; if (ix<2400) ((float4*)Al)[ix] = ta[q]; }
      __syncthreads();
      #pragma unroll
      for (int tap=0; tap<10; ++tap){
        int dh = (tap<9) ? tap/3 : 1;
        int dw = (tap<9) ? (tap - (tap/3)*3) : 1;
        bf16x8 a0 = *(const bf16x8*)&Al[(tap*48 +  0 + n)*40 + kq*8];
        bf16x8 a1 = *(const bf16x8*)&Al[(tap*48 + 16 + n)*40 + kq*8];
        bf16x8 a2 = *(const bf16x8*)&Al[(tap*48 + 32 + n)*40 + kq*8];
        bf16x8 b0 = *(const bf16x8*)&Bl[((0+dh)*66 + wv*16 + dw + n)*40 + kq*8];
        bf16x8 b1 = *(const bf16x8*)&Bl[((1+dh)*66 + wv*16 + dw + n)*40 + kq*8];
        if (tap<9){
          accN[0][0] = __builtin_amdgcn_mfma_f32_16x16x32_bf16(a0, b0, accN[0][0], 0,0,0);
          accN[0][1] = __builtin_amdgcn_mfma_f32_16x16x32_bf16(a1, b0, accN[0][1], 0,0,0);
          accN[0][2] = __builtin_amdgcn_mfma_f32_16x16x32_bf16(a2, b0, accN[0][2], 0,0,0);
          accN[1][0] = __builtin_amdgcn_mfma_f32_16x16x32_bf16(a0, b1, accN[1][0], 0,0,0);
          accN[1][1] = __builtin_amdgcn_mfma_f32_16x16x32_bf16(a1, b1, accN[1][1], 0,0,0);
          accN[1][2] = __builtin_amdgcn_mfma_f32_16x16x32_bf16(a2, b1, accN[1][2], 0,0,0);
        } else {
          accD[t][0][0] = __builtin_amdgcn_mfma_f32_16x16x32_bf16(a0, b0, accD[t][0][0], 0,0,0);
          accD[t][0][1] = __builtin_amdgcn_mfma_f32_16x16x32_bf16(a1, b0, accD[t][0][1], 0,0,0);
          accD[t][0][2] = __builtin_amdgcn_mfma_f32_16x16x32_bf16(a2, b0, accD[t][0][2], 0,0,0);
          accD[t][1][0] = __builtin_amdgcn_mfma_f32_16x16x32_bf16(a0, b1, accD[t][1][0], 0,0,0);
          accD[t][1][1] = __builtin_amdgcn_mfma_f32_16x16x32_bf16(a1, b1, accD[t][1][1], 0,0,0);
          accD[t][1][2] = __builtin_amdgcn_mfma_f32_16x16x32_bf16(a2, b1, accD[t][1][2], 0,0,0);
        }
      }
      __syncthreads();
    }
  }
  // epilogue: plain stores (every XDBL element written exactly once)
  #pragma unroll
  for (int q=0;q<2;++q){
    int hw = (hp*2+q)*64 + wv*16 + n;
    #pragma unroll
    for (int mt=0; mt<3; ++mt){
      #pragma unroll
      for (int r=0;r<4;++r){
        int m = mt*16 + kq*4 + r;
        if (m<38){
          long base = ((long)((b*4+kg)*38+m)<<13) + hw;
          float vN = accN[q][mt][r];
          xdbl[base]        = vN - THETA*accD[0][q][mt][r];
          xdbl[base + 4096] = vN - THETA*accD[1][q][mt][r];
        }
      }
    }
  }
}

// ---------------- K5: delta precompute. 1 wave per (chain, 512-chunk). ----------------
__global__ __launch_bounds__(256) void k_delta(const float* __restrict__ xdbl, const float* __restrict__ xtt,
    const float* __restrict__ dt_w, const float* __restrict__ dt_b,
    u32* __restrict__ ddu, float* __restrict__ S, float* __restrict__ send){
  int wv = threadIdx.x>>6, lane = threadIdx.x&63;
  int gw = blockIdx.x*4 + wv;                 // < 24576
  int chunk = gw & 15; int chain = gw >> 4;   // chain = (b*4+k)*192 + d
  int d = chain % 192; int kb = chain/192; int k = kb & 3; int b = kb >> 2;
  bool rev = (k&1);
  const float* xrow = xdbl + ((long)kb*38<<13);
  float dtw[6];
  #pragma unroll
  for (int r=0;r<6;++r) dtw[r] = dt_w[(k*192+d)*6 + r];
  float dtb = dt_b[k*192+d];
  int l0 = chunk*512 + lane*8;
  float dts[6][8];
  #pragma unroll
  for (int r=0;r<6;++r){
    *(float4*)&dts[r][0] = *(const float4*)&xrow[((long)r<<13) + l0];
    *(float4*)&dts[r][4] = *(const float4*)&xrow[((long)r<<13) + l0 + 4];
  }
  float u8[8];
  {
    const float* ub = xtt + ((long)(b*192+d)<<13);
    float tmp[8];
    long base = rev ? (long)(8191 - l0 - 7) : (long)l0;
    *(float4*)&tmp[0] = *(const float4*)&ub[base];
    *(float4*)&tmp[4] = *(const float4*)&ub[base+4];
    #pragma unroll
    for (int j=0;j<8;++j) u8[j] = rev ? tmp[7-j] : tmp[j];
  }
  float del[8], pre[8]; float run = 0.f;
  #pragma unroll
  for (int j=0;j<8;++j){
    float s = dtb;
    #pragma unroll
    for (int r=0;r<6;++r) s += dts[r][j]*dtw[r];
    float dv = softplusf(s);
    del[j] = dv; run += dv; pre[j] = run;
  }
  float p = run;
  #pragma unroll
  for (int off=1; off<64; off<<=1){
    float t = __shfl_up(p, off);
    if (lane>=off) p += t;
  }
  float excl = p - run;
  {
    float so[8]; u32 po[8];
    #pragma unroll
    for (int j=0;j<8;++j){
      so[j] = excl + pre[j];
      po[j] = ((u32)f2b(del[j])<<16) | (u32)f2b(del[j]*u8[j]);
    }
    float* Sp = S + (long)chain*8192 + l0;
    *(float4*)&Sp[0] = *(float4*)&so[0];
    *(float4*)&Sp[4] = *(float4*)&so[4];
    u32* Dp = ddu + (long)chain*8192 + l0;
    *(uint4*)&Dp[0] = *(uint4*)&po[0];
    *(uint4*)&Dp[4] = *(uint4*)&po[4];
  }
  if (lane==63) send[chunk*1536 + chain] = p;
}

// ---------------- K6a: lean chunked scan. C=16 chunks of 512 ----------------
__global__ __launch_bounds__(64) void k_scan_a(const float* __restrict__ xdbl, const float* __restrict__ xtt,
    const u32* __restrict__ ddu, const float* __restrict__ A_logs, const float* __restrict__ Ds,
    float* __restrict__ outy, float* __restrict__ hend){
  __shared__ u32 ddu2[4][32];
  __shared__ float uls[4][33];
  __shared__ __align__(16) float2 BCl[16][17];
  __shared__ __align__(16) float P[4][328];
  __shared__ float Dl[4];
  int tid = threadIdx.x; int n = tid&15; int dl = tid>>4;
  int th = tid&31, hf = tid>>5;
  int dg = blockIdx.x; int k = blockIdx.y; int zz = blockIdx.z;
  int b = zz>>4; int c = zz&15;
  int dbase = dg*4; bool rev = (k&1);
  if (tid<4) Dl[tid] = Ds[k*192 + dbase + tid];
  float Aval2 = -__expf(A_logs[(k*192 + dbase + dl)*16 + n]) * LOG2E;
  long chainb = (long)(b*4+k)*192 + dbase;
  const float* xrow = xdbl + ((long)(b*4+k)*38<<13);
  float h = 0.f;
  int nr = tid>>2, t4 = (tid&3)*4;
  __syncthreads();
  for (int ph=0; ph<16; ++ph){
    int l0 = c*512 + ph*32;
    {
      const u32* src = ddu + (chainb + (tid>>4))*8192 + l0 + (tid&15)*2;
      uint2 v = *(const uint2*)src;
      *(uint2*)&ddu2[tid>>4][(tid&15)*2] = v;
    }
    #pragma unroll
    for (int q=0;q<2;++q){ int j = q*2+hf;
      long li = rev ? (long)(8191-(l0+th)) : (long)(l0+th);
      uls[j][th] = xtt[((long)(b*192 + dbase + j)<<13) + li];
    }
    __syncthreads();
    #pragma unroll
    for (int h2=0; h2<2; ++h2){
      int lh = l0 + h2*16;
      {
        float4 vB = *(const float4*)&xrow[((long)(6+nr)<<13) + lh + t4];
        float4 vC = *(const float4*)&xrow[((long)(22+nr)<<13) + lh + t4];
        const float* pb = &vB.x; const float* pc = &vC.x;
        #pragma unroll
        for (int e=0;e<4;++e){
          int t = t4+e;
          BCl[t][(nr+t)&15] = make_float2(pb[e], pc[e]);
        }
      }
      __syncthreads();
      #pragma unroll
      for (int s=0; s<16; ++s){
        u32 dd = ddu2[dl][h2*16+s];
        float del = __uint_as_float(dd & 0xFFFF0000u);
        float du  = __uint_as_float(dd << 16);
        float2 bc = BCl[s][(n+s)&15];
        float a = exp2f(del * Aval2);
        h = fmaf(a, h, du * bc.x);
        P[dl][s*20+n] = h * bc.y;
      }
      __syncthreads();
      {
        int j = tid>>4, tq = tid&15;
        const float4* pr = (const float4*)&P[j][tq*20];
        float4 q0=pr[0], q1=pr[1], q2=pr[2], q3=pr[3];
        float y = ((q0.x+q0.y)+(q0.z+q0.w)) + ((q1.x+q1.y)+(q1.z+q1.w))
                + ((q2.x+q2.y)+(q2.z+q2.w)) + ((q3.x+q3.y)+(q3.z+q3.w));
        int tt = h2*16 + tq;
        outy[((chainb+j)<<13) + l0 + tt] = y + Dl[j]*uls[j][tt];
      }
      __syncthreads();
    }
  }
  long chain = chainb + dl;
  hend[c*24576 + chain*16 + n] = h;
}

// ---------------- K6b: carry propagation across the 16 chunks ----------------
__global__ __launch_bounds__(256) void k_scan_b(const float* __restrict__ A_logs,
    const float* __restrict__ hend, const float* __restrict__ send, float* __restrict__ h0g){
  int idx = blockIdx.x*256 + threadIdx.x;   // < 24576
  int chain = idx>>4, n = idx&15;
  int d = chain%192; int kk = (chain/192)&3;
  float A2 = -__expf(A_logs[(kk*192+d)*16+n]) * LOG2E;
  float h0 = 0.f;
  #pragma unroll
  for (int c=0;c<15;++c){
    h0 = exp2f(A2*send[c*1536+chain])*h0 + hend[c*24576+idx];
    h0g[(c+1)*24576 + idx] = h0;
  }
}

// ---------------- K6c: fix-up for chunks 1..15; d-quarters, prefetched ----------------
__global__ __launch_bounds__(128) void k_scan_c(const float* __restrict__ xdbl,
    const float* __restrict__ A_logs, const float* __restrict__ S, const float* __restrict__ h0g,
    float* __restrict__ outy){
  __shared__ float Cl[16][132];
  __shared__ float Al[48][16];
  __shared__ float h0l[48][16];
  int tid = threadIdx.x;
  int tt0 = blockIdx.x*128; int c = blockIdx.y+1; int z = blockIdx.z;
  int kb = z>>2, dq = z&3;
  int k = kb&3; int d0 = dq*48;
  const float* xrow = xdbl + ((long)kb*38<<13);
  for (int idx=tid; idx<2048; idx+=128){
    int nn = idx>>7, t = idx&127;
    Cl[nn][t] = xrow[((long)(22+nn)<<13) + c*512 + tt0 + t];
  }
  for (int idx=tid; idx<768; idx+=128){
    int d = idx>>4, nn = idx&15;
    h0l[d][nn] = h0g[c*24576 + (kb*192 + d0 + d)*16 + nn];
    Al[d][nn]  = -__expf(A_logs[(k*192 + d0 + d)*16 + nn]) * LOG2E;
  }
  __syncthreads();
  int t = tt0 + tid;
  long sb = (long)(kb*192 + d0)*8192 + c*512 + t;
  float Sv = S[sb];
  for (int d=0; d<48; ++d){
    float Sn = (d<47) ? S[sb + (long)(d+1)*8192] : 0.f;
    long yi = ((long)(kb*192 + d0 + d)<<13) + c*512 + t;
    float yv = outy[yi];
    float acc = 0.f;
    #pragma unroll
    for (int nn=0; nn<16; ++nn) acc += Cl[nn][tid]*exp2f(Al[d][nn]*Sv)*h0l[d][nn];
    outy[yi] = yv + acc;
    Sv = Sn;
  }
}

// ---------------- K7a: per-frame 64x64 spatial transpose ----------------
__global__ __launch_bounds__(256) void k_transp(const float* __restrict__ outy, float* __restrict__ T1,
     float* __restrict__ T3){
  __shared__ float tl[64*65];
  int idx = blockIdx.x;         // < 1536
  int t = idx&1; int q = idx>>1; int d = q%192; int r2 = q/192; int ksel = r2&1; int b = r2>>1;
  int k = ksel ? 3 : 1;
  const float* src = outy + ((long)((b*4+k)*192 + d)<<13) + t*4096;
  float* dst = (ksel ? T3 : T1) + ((long)(b*192 + d)<<13) + t*4096;
  int tid = threadIdx.x;
  for (int i=tid; i<4096; i+=256){ int r=i>>6, c=i&63; tl[c*65+r] = src[i]; }
  __syncthreads();
  for (int i=tid; i<4096; i+=256){ int r=i>>6, c=i&63; dst[i] = tl[r*65+c]; }
}

// ---------------- K7b: 8-term combine + out-LN + silu(z) gate -> Y ----------------
__global__ __launch_bounds__(256) void k_combine(const float* __restrict__ outy,
    const float* __restrict__ T1, const float* __restrict__ T3,
    const float* __restrict__ z, const float* __restrict__ ong, const float* __restrict__ onb,
    float* __restrict__ Y){
  __shared__ float yt[32][193];
  __shared__ float redl[32][8][2];
  __shared__ float stats[32][2];
  int tid = threadIdx.x;
  int tx = tid&31, ty = tid>>5;
  int b = blockIdx.y;
  long pg = (long)(blockIdx.x&127)*32 + tx;
  float s = 0.f, s2 = 0.f;
  #pragma unroll 4
  for (int dc=0; dc<24; ++dc){
    int d = dc*8 + ty;
    const float* r0 = outy + ((long)(b*768 + d)<<13);
    const float* r2 = outy + ((long)(b*768 + 384 + d)<<13);
    const float* t1 = T1 + ((long)(b*192 + d)<<13);
    const float* t3 = T3 + ((long)(b*192 + d)<<13);
    float v = r0[pg] + r0[4096+pg] + r2[8191-pg] + r2[4095-pg]
            + t1[pg] + t1[4096+pg] + t3[8191-pg] + t3[4095-pg];
    yt[tx][d] = v; s += v; s2 += v*v;
  }
  redl[tx][ty][0] = s; redl[tx][ty][1] = s2;
  __syncthreads();
  if (tid<32){
    float Sx=0.f, S2=0.f;
    #pragma unroll
    for (int g=0; g<8; ++g){ Sx += redl[tid][g][0]; S2 += redl[tid][g][1]; }
    float m = Sx*(1.f/192.f);
    float var = fmaxf(S2*(1.f/192.f) - m*m, 0.f);
    stats[tid][0] = m; stats[tid][1] = rsqrtf(var + 1e-5f);
  }
  __syncthreads();
  long rowbase = (long)b*4096 + (blockIdx.x&127)*32;
  #pragma unroll 4
  for (int idx=tid; idx<32*192; idx+=256){
    int r = idx/192, d = idx - r*192;
    float v = (yt[r][d] - stats[r][0])*stats[r][1]*ong[d] + onb[d];
    float zv = z[(rowbase+r)*192 + d];
    Y[(rowbase+r)*192 + d] = v*(zv*sigm(zv));
  }
}

// ---------------- K7c: out0 = xc + Y @ wout ----------------
__global__ __launch_bounds__(256) void k_outproj(const float* __restrict__ Y,
    const float* __restrict__ xc, const float* __restrict__ wout, float* __restrict__ out0){
  __shared__ float Yl[32][193];
  __shared__ __align__(16) float Wl[48*96];
  int tid = threadIdx.x;
  int r = tid>>3, cq = tid&7;
  long rowbase = (long)blockIdx.x*32;
  for (int idx=tid; idx<32*192; idx+=256){
    int rr = idx/192, d = idx - rr*192;
    Yl[rr][d] = Y[(rowbase+rr)*192 + d];
  }
  float acc[12] = {};
  for (int db=0; db<192; db+=48){
    __syncthreads();
    for (int idx=tid; idx<48*96; idx+=256) Wl[idx] = wout[db*96 + idx];
    __syncthreads();
    #pragma unroll 4
    for (int dd=0; dd<48; ++dd){
      float yv = Yl[r][db+dd];
      const float4* wr = (const float4*)&Wl[dd*96 + cq*12];
      float4 w0=wr[0], w1=wr[1], w2=wr[2];
      acc[0]+=yv*w0.x; acc[1]+=yv*w0.y; acc[2]+=yv*w0.z;  acc[3]+=yv*w0.w;
      acc[4]+=yv*w1.x; acc[5]+=yv*w1.y; acc[6]+=yv*w1.z;  acc[7]+=yv*w1.w;
      acc[8]+=yv*w2.x; acc[9]+=yv*w2.y; acc[10]+=yv*w2.z; acc[11]+=yv*w2.w;
    }
  }
  long ob = (rowbase + r)*96 + cq*12;
  #pragma unroll
  for (int j=0;j<12;++j) out0[ob+j] = xc[ob+j] + acc[j];
}

extern "C" void kernel_launch(void* const* d_in, const int* in_sizes, int n_in,
                              void* d_out, int out_size, void* d_ws, size_t ws_size,
                              hipStream_t stream) {
  const float* input0    = (const float*)d_in[0];
  const float* input1    = (const float*)d_in[1];
  const float* ln1_g     = (const float*)d_in[2];
  const float* ln1_b     = (const float*)d_in[3];
  const float* in_proj_w = (const float*)d_in[4];
  const float* conv2d_w  = (const float*)d_in[5];
  const float* conv2d_b  = (const float*)d_in[6];
  const float* conv2dxt_w= (const float*)d_in[7];
  const float* conv2dxt_b= (const float*)d_in[8];
  const float* x_proj_w  = (const float*)d_in[9];
  const float* dt_w      = (const float*)d_in[10];
  const float* dt_b      = (const float*)d_in[11];
  const float* A_logs    = (const float*)d_in[12];
  const float* Ds_       = (const float*)d_in[13];
  const float* ong       = (const float*)d_in[14];
  const float* onb       = (const float*)d_in[15];
  const float* wout      = (const float*)d_in[16];
  float* out0 = (float*)d_out;
  float* out1 = out0 + 786432;
  float* ws = (float*)d_ws;
  float* XC   = ws;                  // 786432
  float* XT   = XC   + 786432;       // 786432
  float* Z    = XT   + 786432;       // 3145728
  float* XPRE = Z    + 3145728;      // 3145728  dead after k_convx -> reused as Y
  float* XTT  = XPRE + 3145728;      // 6291456
  float* KD   = XTT  + 6291456;      // 29184
  float* XDBL = KD   + 29184;        // 2490368
  float* OUTY = XDBL + 2490368;      // 12582912; doubles as packed DDU (u32) before scan_a writes
  float* T1   = OUTY + 12582912;     // 3145728
  float* T3   = T1   + 3145728;      // 3145728
  float* SCR  = T3   + 3145728;      // 4655104 region for XTNP/WB (bf16)
  float* HEND = SCR  + 4655104;      // 393216 (16 x 24576)
  float* SEND = HEND + 393216;       // 24576  (16 x 1536)
  float* H0   = SEND + 24576;        // 393216
  float* Sarr = H0   + 393216;       // 12582912 (chain x 8192 per-chunk cumsum)
  float* Y    = XPRE;                // reuse
  u16* XTNP = (u16*)SCR;             // 4,181,760 halfs
  u16* WB   = (u16*)(SCR + 4194304); // 921,600 halfs
  u32* DDU  = (u32*)OUTY;            // packed (delta|delta*u) bf16x2

  k_ln    <<<dim3(4096), dim3(256), 0, stream>>>(input0, input1, ln1_g, ln1_b, XC, XT, out1);
  k_inproj<<<dim3(256),  dim3(256), 0, stream>>>(XC, in_proj_w, XPRE, Z);
  k_convx <<<dim3(6144), dim3(256), 0, stream>>>(XPRE, conv2d_w, conv2d_b, XTT);
  k_convxt<<<dim3(6144), dim3(256), 0, stream>>>(XT, conv2dxt_w, conv2dxt_b, XTT);
  k_kd    <<<dim3(114),  dim3(256), 0, stream>>>(x_proj_w, KD);
  k_zero  <<<dim3(2042), dim3(256), 0, stream>>>((float4*)XTNP, 522720);
  k_xtn   <<<dim3(64,6,4), dim3(256), 0, stream>>>(XTT, XTNP);
  k_wb    <<<dim3(3600), dim3(256), 0, stream>>>(x_proj_w, KD, WB);
  k_outn  <<<dim3(32,2,4), dim3(256), 0, stream>>>(XTNP, WB, XDBL);
  k_delta <<<dim3(6144), dim3(256), 0, stream>>>(XDBL, XTT, dt_w, dt_b, DDU, Sarr, SEND);
  k_scan_a<<<dim3(48,4,32), dim3(64), 0, stream>>>(XDBL, XTT, DDU, A_logs, Ds_, OUTY, HEND);
  k_scan_b<<<dim3(96), dim3(256), 0, stream>>>(A_logs, HEND, SEND, H0);
  k_scan_c<<<dim3(4,15,32), dim3(128), 0, stream>>>(XDBL, A_logs, Sarr, H0, OUTY);
  k_transp<<<dim3(1536), dim3(256), 0, stream>>>(OUTY, T1, T3);
  k_combine<<<dim3(128,2), dim3(256), 0, stream>>>(OUTY, T1, T3, Z, ong, onb, Y);
  k_outproj<<<dim3(256),  dim3(256), 0, stream>>>(Y, XC, wout, out0);
}